// Round 3
// baseline (388.546 us; speedup 1.0000x reference)
//
#include <hip/hip_runtime.h>

#define NFEAT 2048
#define BATCH 16384

typedef float  v4f __attribute__((ext_vector_type(4)));  // clang-native for nt-store

// One row per block (4 waves, 8 KB LDS -> occupancy wave-limited at 32/CU).
// Single latency exposure: x is staged to LDS via global_load_lds (async, no
// VGPR round trip) AND the mask/perm loads are issued before the one
// __syncthreads, so all VMEM is in flight together; the barrier's vmcnt(0)
// drain pays max(latency), not sum. Output is stored nontemporally (never
// re-read) to keep L2/L3 for the input stream.
__global__ __launch_bounds__(256) void swap_corrupt_kernel(
    const float* __restrict__ x,
    const int*   __restrict__ mask,
    const int*   __restrict__ perm,
    float*       __restrict__ out)
{
    __shared__ float row[NFEAT];   // 8 KB

    const int t    = threadIdx.x;
    const int lane = t & 63;
    const int w    = t >> 6;           // wave id 0..3
    const size_t base = (size_t)blockIdx.x * NFEAT;

    // ---- stage row into LDS: each wave covers its contiguous 2 KB chunk ----
    // dest is wave-uniform; HW writes lane i at dest + i*16 (16 B/lane).
    const auto* gx   = (const __attribute__((address_space(1))) float*)(x + base);
    auto*       lrow = (__attribute__((address_space(3))) float*)row;
#pragma unroll
    for (int c = 0; c < 2; ++c) {
        const int off = w * 512 + c * 256;   // floats
        __builtin_amdgcn_global_load_lds(
            (const __attribute__((address_space(1))) void*)(gx + off + lane * 4),
            (__attribute__((address_space(3))) void*)(lrow + off),
            16, 0, 0);
    }

    // ---- issue mask/perm loads NOW (same exposure as the staging) ----
    const int4* __restrict__ m4 = (const int4*)(mask + base);
    const int4* __restrict__ p4 = (const int4*)(perm + base);
    int4 m0 = m4[t], m1 = m4[t + 256];
    int4 p0 = p4[t], p1 = p4[t + 256];

    // Single drain + barrier (vmcnt(0) lgkmcnt(0) + s_barrier).
    __syncthreads();

    // ---- gather from LDS, select against pass-through, nontemporal store ----
    v4f* __restrict__ o4 = (v4f*)(out + base);
    {
        float4 a = ((const float4*)row)[t];          // ds_read_b128, conflict-free
        v4f o;
        o.x = m0.x ? row[p0.x] : a.x;
        o.y = m0.y ? row[p0.y] : a.y;
        o.z = m0.z ? row[p0.z] : a.z;
        o.w = m0.w ? row[p0.w] : a.w;
        __builtin_nontemporal_store(o, &o4[t]);
    }
    {
        float4 b = ((const float4*)row)[t + 256];
        v4f o;
        o.x = m1.x ? row[p1.x] : b.x;
        o.y = m1.y ? row[p1.y] : b.y;
        o.z = m1.z ? row[p1.z] : b.z;
        o.w = m1.w ? row[p1.w] : b.w;
        __builtin_nontemporal_store(o, &o4[t + 256]);
    }
}

extern "C" void kernel_launch(void* const* d_in, const int* in_sizes, int n_in,
                              void* d_out, int out_size, void* d_ws, size_t ws_size,
                              hipStream_t stream) {
    const float* x    = (const float*)d_in[0];
    const int*   mask = (const int*)d_in[1];
    const int*   perm = (const int*)d_in[2];
    float*       out  = (float*)d_out;

    swap_corrupt_kernel<<<dim3(BATCH), dim3(256), 0, stream>>>(x, mask, perm, out);
}

// Round 4
// 382.534 us; speedup vs baseline: 1.0157x; 1.0157x over previous
//
#include <hip/hip_runtime.h>

#define NFEAT 2048
#define BATCH 16384

// v0 structure (137 us) + ONE change: pin all six loads (x a/b, mask x2,
// perm x2) in flight before the ds_writes. v0's VGPR_Count=12 proved the
// compiler was sinking each load to its use -> four serialized ~2KB latency
// exposures per row. The asm consume-barrier forces all loads issued
// back-to-back: one latency exposure, ~24KB in flight per block.
__global__ __launch_bounds__(256) void swap_corrupt_kernel(
    const float* __restrict__ x,
    const int*   __restrict__ mask,
    const int*   __restrict__ perm,
    float*       __restrict__ out)
{
    __shared__ float row[NFEAT];   // 8 KB -> wave-slot-limited occupancy (8 blocks/CU)

    const int r = blockIdx.x;
    const int t = threadIdx.x;
    const size_t base = (size_t)r * NFEAT;

    const float4* __restrict__ x4 = (const float4*)(x + base);
    const int4*   __restrict__ m4 = (const int4*)(mask + base);
    const int4*   __restrict__ p4 = (const int4*)(perm + base);

    // ---- issue ALL loads back-to-back (6 x b128 per thread) ----
    float4 a  = x4[t];
    float4 b  = x4[t + 256];
    int4   m0 = m4[t];
    int4   m1 = m4[t + 256];
    int4   p0 = p4[t];
    int4   p1 = p4[t + 256];

    // Consume-barrier: forces every load above to be issued (and its result
    // materialized) before anything below; nothing can sink past this.
    asm volatile("" ::
        "v"(a.x),  "v"(a.y),  "v"(a.z),  "v"(a.w),
        "v"(b.x),  "v"(b.y),  "v"(b.z),  "v"(b.w),
        "v"(m0.x), "v"(m0.y), "v"(m0.z), "v"(m0.w),
        "v"(m1.x), "v"(m1.y), "v"(m1.z), "v"(m1.w),
        "v"(p0.x), "v"(p0.y), "v"(p0.z), "v"(p0.w),
        "v"(p1.x), "v"(p1.y), "v"(p1.z), "v"(p1.w));

    // ---- stage row in LDS (conflict-free b128 writes) ----
    ((float4*)row)[t]       = a;
    ((float4*)row)[t + 256] = b;
    __syncthreads();

    float4* __restrict__ o4 = (float4*)(out + base);

    // ---- gather: pass-through from REGISTERS, LDS only for swapped lanes ----
    {
        float4 o;
        o.x = m0.x ? row[p0.x] : a.x;
        o.y = m0.y ? row[p0.y] : a.y;
        o.z = m0.z ? row[p0.z] : a.z;
        o.w = m0.w ? row[p0.w] : a.w;
        o4[t] = o;
    }
    {
        float4 o;
        o.x = m1.x ? row[p1.x] : b.x;
        o.y = m1.y ? row[p1.y] : b.y;
        o.z = m1.z ? row[p1.z] : b.z;
        o.w = m1.w ? row[p1.w] : b.w;
        o4[t + 256] = o;
    }
}

extern "C" void kernel_launch(void* const* d_in, const int* in_sizes, int n_in,
                              void* d_out, int out_size, void* d_ws, size_t ws_size,
                              hipStream_t stream) {
    const float* x    = (const float*)d_in[0];
    const int*   mask = (const int*)d_in[1];
    const int*   perm = (const int*)d_in[2];
    float*       out  = (float*)d_out;

    swap_corrupt_kernel<<<dim3(BATCH), dim3(256), 0, stream>>>(x, mask, perm, out);
}